// Round 2
// baseline (522.397 us; speedup 1.0000x reference)
//
#include <hip/hip_runtime.h>
#include <hip/hip_cooperative_groups.h>
#include <math.h>

namespace cg = cooperative_groups;

#define EMB 8
#define SEQ 1024
#define NBATCH 32
#define NROWS (NBATCH * SEQ)
#define LNEPS 1e-5f
#define NWG 512            // 16 workgroups per batch, 64 rows each, 4 thr/row

// Closed-form quantum head: RX layer + Clifford (CNOT chain + H) conjugates
// each Z_i to a product of cos(x_j) (even/odd prefix products).
__device__ __forceinline__ void qhead(const float xv[8], float z[8]) {
    float c[8];
#pragma unroll
    for (int j = 0; j < 8; ++j) c[j] = __cosf(xv[j]);
    float e0 = c[0];
    float o1 = c[1];
    float e2 = e0 * c[2];
    float o3 = o1 * c[3];
    float e4 = e2 * c[4];
    float o5 = o3 * c[5];
    float e6 = e4 * c[6];
    z[0] = e0; z[1] = o1; z[2] = e2; z[3] = o3;
    z[4] = e4; z[5] = o5; z[6] = e6;
    z[7] = e6 * o5 * c[7];
}

__global__ __launch_bounds__(256, 2) void qt_all(
    const int* __restrict__ tokens, const float* __restrict__ emb,
    const float* __restrict__ attn_w, const float* __restrict__ attn_b,
    const float* __restrict__ ln1_g, const float* __restrict__ ln1_b,
    const float* __restrict__ ffn_w1, const float* __restrict__ ffn_b1,
    const float* __restrict__ ffn_w2, const float* __restrict__ ffn_b2,
    const float* __restrict__ ln2_g, const float* __restrict__ ln2_b,
    const float* __restrict__ cls_w, const float* __restrict__ cls_b,
    float* __restrict__ qkv, float* __restrict__ partial,
    float* __restrict__ out)
{
    cg::grid_group grid = cg::this_grid();
    __shared__ float4 ks[SEQ * 2];     // 32 KB: this batch's qkv
    __shared__ float ws2[4][8];

    const int wg = blockIdx.x;
    const int b = wg >> 4;
    const int chunk = wg & 15;
    const int tid = threadIdx.x;
    const int phase = tid & 3;         // 4 threads per query row
    const int row = chunk * 64 + (tid >> 2);     // row within batch
    const long grow = (long)b * SEQ + row;

    // ---------------- embed + posenc + first qhead ----------------
    // (all 4 phases compute the row redundantly; x lives in registers forever)
    float xv[8];
    {
        int tok = tokens[grow];
        const float* e = emb + (long)tok * EMB;
        float p = (float)row;
        xv[0] = e[0] + sinf(p);
        xv[1] = e[1] + cosf(p);
        xv[2] = e[2] + sinf(p * 0.1f);
        xv[3] = e[3] + cosf(p * 0.1f);
        xv[4] = e[4] + sinf(p * 0.01f);
        xv[5] = e[5] + cosf(p * 0.01f);
        xv[6] = e[6] + sinf(p * 0.001f);
        xv[7] = e[7] + cosf(p * 0.001f);
        float z[8]; qhead(xv, z);
        if (phase == 0) {
            float4* qo = (float4*)(qkv + grow * 8);
            qo[0] = make_float4(z[0], z[1], z[2], z[3]);
            qo[1] = make_float4(z[4], z[5], z[6], z[7]);
        }
    }
    grid.sync();

    // 1/sqrt(8) * log2(e): fold softmax scale + exp->exp2 into q
    const float qscale = 0.35355339059327373f * 1.4426950408889634f;

    for (int l = 0; l < 6; ++l) {
        // ---- stage this batch's qkv into LDS ----
        const float4* src = (const float4*)(qkv + (long)b * SEQ * EMB);
        for (int i = tid; i < SEQ * 2; i += 256) ks[i] = src[i];
        __syncthreads();

        float4 q0 = ks[2 * row], q1 = ks[2 * row + 1];
        float q[8];
        q[0] = q0.x * qscale; q[1] = q0.y * qscale; q[2] = q0.z * qscale; q[3] = q0.w * qscale;
        q[4] = q1.x * qscale; q[5] = q1.y * qscale; q[6] = q1.z * qscale; q[7] = q1.w * qscale;

        float acc[8] = {0, 0, 0, 0, 0, 0, 0, 0};
        float sum = 0.f;
#pragma unroll 4
        for (int j = 0; j < SEQ / 4; ++j) {
            int k = (j << 2) | phase;
            float4 k0 = ks[2 * k], k1 = ks[2 * k + 1];
            float s = q[0] * k0.x + q[1] * k0.y + q[2] * k0.z + q[3] * k0.w
                    + q[4] * k1.x + q[5] * k1.y + q[6] * k1.z + q[7] * k1.w;
            float ev = exp2f(s);
            sum += ev;
            acc[0] += ev * k0.x; acc[1] += ev * k0.y; acc[2] += ev * k0.z; acc[3] += ev * k0.w;
            acc[4] += ev * k1.x; acc[5] += ev * k1.y; acc[6] += ev * k1.z; acc[7] += ev * k1.w;
        }
        // combine the row's 4 key-phases
        sum += __shfl_xor(sum, 1); sum += __shfl_xor(sum, 2);
#pragma unroll
        for (int j = 0; j < 8; ++j) {
            acc[j] += __shfl_xor(acc[j], 1);
            acc[j] += __shfl_xor(acc[j], 2);
        }
        float inv = 1.0f / sum;

        // ---- proj + residual + LN1 (redundant across phases) ----
        const float* W = attn_w + l * 64;
        const float* bi = attn_b + l * 8;
        float y[8]; float m = 0.f;
#pragma unroll
        for (int j = 0; j < 8; ++j) {
            float v = bi[j];
#pragma unroll
            for (int i = 0; i < 8; ++i) v += (acc[i] * inv) * W[i * 8 + j];
            y[j] = xv[j] + v;
            m += y[j];
        }
        m *= 0.125f;
        float var = 0.f;
#pragma unroll
        for (int j = 0; j < 8; ++j) { float d = y[j] - m; var += d * d; }
        var *= 0.125f;
        float rs = rsqrtf(var + LNEPS);
        const float* g1 = ln1_g + l * 8; const float* b1v = ln1_b + l * 8;
        float xn[8];
#pragma unroll
        for (int j = 0; j < 8; ++j) xn[j] = g1[j] * (y[j] - m) * rs + b1v[j];

        // ---- FFN: 8x8 -> qhead -> 8x8, residual + LN2 ----
        const float* W1 = ffn_w1 + l * 64; const float* c1 = ffn_b1 + l * 8;
        const float* W2 = ffn_w2 + l * 64; const float* c2 = ffn_b2 + l * 8;
        float h[8];
#pragma unroll
        for (int j = 0; j < 8; ++j) {
            float v = c1[j];
#pragma unroll
            for (int i = 0; i < 8; ++i) v += xn[i] * W1[i * 8 + j];
            h[j] = v;
        }
        float qf[8]; qhead(h, qf);
        float m2 = 0.f;
#pragma unroll
        for (int j = 0; j < 8; ++j) {
            float v = c2[j];
#pragma unroll
            for (int i = 0; i < 8; ++i) v += qf[i] * W2[i * 8 + j];
            y[j] = xn[j] + v;
            m2 += y[j];
        }
        m2 *= 0.125f;
        float var2 = 0.f;
#pragma unroll
        for (int j = 0; j < 8; ++j) { float d = y[j] - m2; var2 += d * d; }
        var2 *= 0.125f;
        float rs2 = rsqrtf(var2 + LNEPS);
        const float* g2 = ln2_g + l * 8; const float* b2v = ln2_b + l * 8;
#pragma unroll
        for (int j = 0; j < 8; ++j) xv[j] = g2[j] * (y[j] - m2) * rs2 + b2v[j];

        // ---- next layer's qkv ----
        if (l < 5) {
            float z[8]; qhead(xv, z);
            if (phase == 0) {
                float4* qo = (float4*)(qkv + grow * 8);
                qo[0] = make_float4(z[0], z[1], z[2], z[3]);
                qo[1] = make_float4(z[4], z[5], z[6], z[7]);
            }
        }
        grid.sync();
    }

    // ---------------- pool: per-wg partial sums ----------------
    // every lane holds its row's final x (4x phase duplication) ->
    // full-wave butterfly sums 16 rows x4; scale by 0.25.
    float a[8];
#pragma unroll
    for (int j = 0; j < 8; ++j) a[j] = xv[j];
#pragma unroll
    for (int j = 0; j < 8; ++j) {
#pragma unroll
        for (int off = 1; off <= 32; off <<= 1) a[j] += __shfl_xor(a[j], off);
        a[j] *= 0.25f;
    }
    int wave = tid >> 6, lane = tid & 63;
    if (lane == 0) {
#pragma unroll
        for (int j = 0; j < 8; ++j) ws2[wave][j] = a[j];
    }
    __syncthreads();
    if (tid < 8) {
        partial[wg * 8 + tid] = ws2[0][tid] + ws2[1][tid] + ws2[2][tid] + ws2[3][tid];
    }
    grid.sync();

    // ---------------- classifier: wg b handles batch b ----------------
    if (wg < NBATCH && tid < 10) {
        float o = cls_b[tid];
#pragma unroll
        for (int j = 0; j < 8; ++j) {
            float pj = 0.f;
#pragma unroll
            for (int i = 0; i < 16; ++i) pj += partial[(wg * 16 + i) * 8 + j];
            o += pj * (1.0f / 1024.0f) * cls_w[j * 10 + tid];
        }
        out[wg * 10 + tid] = o;
    }
}

extern "C" void kernel_launch(void* const* d_in, const int* in_sizes, int n_in,
                              void* d_out, int out_size, void* d_ws, size_t ws_size,
                              hipStream_t stream) {
    const int*   tokens = (const int*)d_in[0];
    const float* emb    = (const float*)d_in[1];
    const float* ln1_g  = (const float*)d_in[2];
    const float* ln1_b  = (const float*)d_in[3];
    const float* ln2_g  = (const float*)d_in[4];
    const float* ln2_b  = (const float*)d_in[5];
    const float* attn_w = (const float*)d_in[6];
    const float* attn_b = (const float*)d_in[7];
    const float* ffn_w1 = (const float*)d_in[8];
    const float* ffn_b1 = (const float*)d_in[9];
    const float* ffn_w2 = (const float*)d_in[10];
    const float* ffn_b2 = (const float*)d_in[11];
    const float* cls_w  = (const float*)d_in[12];
    const float* cls_b  = (const float*)d_in[13];

    float* qkv     = (float*)d_ws;                    // NROWS*8 f32 = 1 MB
    float* partial = qkv + (long)NROWS * 8;           // NWG*8 f32 = 16 KB
    float* outp    = (float*)d_out;

    void* args[] = {
        (void*)&tokens, (void*)&emb,
        (void*)&attn_w, (void*)&attn_b,
        (void*)&ln1_g, (void*)&ln1_b,
        (void*)&ffn_w1, (void*)&ffn_b1,
        (void*)&ffn_w2, (void*)&ffn_b2,
        (void*)&ln2_g, (void*)&ln2_b,
        (void*)&cls_w, (void*)&cls_b,
        (void*)&qkv, (void*)&partial, (void*)&outp,
    };
    hipLaunchCooperativeKernel((const void*)qt_all, dim3(NWG), dim3(256),
                               args, 0, stream);
}

// Round 3
// 203.754 us; speedup vs baseline: 2.5639x; 2.5639x over previous
//
#include <hip/hip_runtime.h>
#include <math.h>

#define EMB 8
#define SEQ 1024
#define NBATCH 32
#define NROWS (NBATCH * SEQ)
#define LNEPS 1e-5f

// Closed-form quantum head: RX layer + Clifford (CNOT chain + H) conjugates
// each Z_i into a product of cos(x_j) (even/odd prefix products).
__device__ __forceinline__ void qhead(const float xv[8], float z[8]) {
    float c[8];
#pragma unroll
    for (int j = 0; j < 8; ++j) c[j] = __cosf(xv[j]);
    float e0 = c[0];
    float o1 = c[1];
    float e2 = e0 * c[2];
    float o3 = o1 * c[3];
    float e4 = e2 * c[4];
    float o5 = o3 * c[5];
    float e6 = e4 * c[6];
    z[0] = e0; z[1] = o1; z[2] = e2; z[3] = o3;
    z[4] = e4; z[5] = o5; z[6] = e6;
    z[7] = e6 * o5 * c[7];
}

// x = emb[tokens] + posenc ; qkv = qhead(x)
__global__ __launch_bounds__(256) void embed_kernel(
    const int* __restrict__ tokens, const float* __restrict__ emb,
    float* __restrict__ x, float* __restrict__ qkv)
{
    int r = blockIdx.x * 256 + threadIdx.x;
    int s = r & (SEQ - 1);
    int tok = tokens[r];
    const float* e = emb + (long)tok * EMB;
    float p = (float)s;
    float xv[8];
    xv[0] = e[0] + sinf(p);
    xv[1] = e[1] + cosf(p);
    xv[2] = e[2] + sinf(p * 0.1f);
    xv[3] = e[3] + cosf(p * 0.1f);
    xv[4] = e[4] + sinf(p * 0.01f);
    xv[5] = e[5] + cosf(p * 0.01f);
    xv[6] = e[6] + sinf(p * 0.001f);
    xv[7] = e[7] + cosf(p * 0.001f);
    float z[8]; qhead(xv, z);
    float4* xo = (float4*)(x + (long)r * 8);
    float4* qo = (float4*)(qkv + (long)r * 8);
    xo[0] = make_float4(xv[0], xv[1], xv[2], xv[3]);
    xo[1] = make_float4(xv[4], xv[5], xv[6], xv[7]);
    qo[0] = make_float4(z[0], z[1], z[2], z[3]);
    qo[1] = make_float4(z[4], z[5], z[6], z[7]);
}

// One full transformer block: attention (R=4 rows/thread, 16 key-phases)
// + proj + LN1 + FFN(qhead) + LN2 + next-layer qhead, all fused.
__global__ __launch_bounds__(256, 4) void layer_kernel(
    float* __restrict__ x, float* __restrict__ qkv,
    const float* __restrict__ W, const float* __restrict__ Wb,
    const float* __restrict__ g1, const float* __restrict__ b1v,
    const float* __restrict__ W1, const float* __restrict__ c1,
    const float* __restrict__ W2, const float* __restrict__ c2,
    const float* __restrict__ g2, const float* __restrict__ b2v)
{
    __shared__ float4 ks[SEQ * 2];   // 32 KB, linear layout
    const int b = blockIdx.y;
    const int tid = threadIdx.x;
    const int p = tid & 15;          // key phase: this thread handles k ≡ p (mod 16)
    const int grp = tid >> 4;        // row group (4 rows each)
    const int row0 = blockIdx.x * 64 + grp * 4;

    const float4* src = (const float4*)(qkv + (long)b * SEQ * EMB);
    for (int i = tid; i < SEQ * 2; i += 256) ks[i] = src[i];
    __syncthreads();

    // Read-order swizzle: lane reads its key's two 16B halves in order
    // (sw, 1-sw); makes per-instruction bank residues 2-way (free).
    const int sw = ((p >> 2) ^ (p >> 3)) & 1;
    const float qscale = 0.35355339059327373f * 1.4426950408889634f; // log2e/sqrt(8)

    float qA[4][4], qB[4][4];
#pragma unroll
    for (int r = 0; r < 4; ++r) {
        float4 ha = ks[2 * (row0 + r) + sw];
        float4 hb = ks[2 * (row0 + r) + (sw ^ 1)];
        qA[r][0] = ha.x * qscale; qA[r][1] = ha.y * qscale;
        qA[r][2] = ha.z * qscale; qA[r][3] = ha.w * qscale;
        qB[r][0] = hb.x * qscale; qB[r][1] = hb.y * qscale;
        qB[r][2] = hb.z * qscale; qB[r][3] = hb.w * qscale;
    }

    float accA[4][4] = {{0}}, accB[4][4] = {{0}};
    float sum[4] = {0, 0, 0, 0};
#pragma unroll 2
    for (int j = 0; j < SEQ / 16; ++j) {
        int k = (j << 4) | p;
        float4 kA = ks[2 * k + sw];
        float4 kB = ks[2 * k + (sw ^ 1)];
#pragma unroll
        for (int r = 0; r < 4; ++r) {
            float s = qA[r][0] * kA.x + qA[r][1] * kA.y + qA[r][2] * kA.z + qA[r][3] * kA.w
                    + qB[r][0] * kB.x + qB[r][1] * kB.y + qB[r][2] * kB.z + qB[r][3] * kB.w;
            float ev = exp2f(s);
            sum[r] += ev;
            accA[r][0] += ev * kA.x; accA[r][1] += ev * kA.y;
            accA[r][2] += ev * kA.z; accA[r][3] += ev * kA.w;
            accB[r][0] += ev * kB.x; accB[r][1] += ev * kB.y;
            accB[r][2] += ev * kB.z; accB[r][3] += ev * kB.w;
        }
    }
    // un-swizzle halves back to canonical order
    float acc[4][8];
#pragma unroll
    for (int r = 0; r < 4; ++r)
#pragma unroll
        for (int i = 0; i < 4; ++i) {
            acc[r][i]     = sw ? accB[r][i] : accA[r][i];
            acc[r][4 + i] = sw ? accA[r][i] : accB[r][i];
        }

    // stage 1: combine phase-classes mod 4 (xor 4, 8) — all 4 rows
#pragma unroll
    for (int off = 4; off <= 8; off <<= 1) {
#pragma unroll
        for (int r = 0; r < 4; ++r) {
            sum[r] += __shfl_xor(sum[r], off);
#pragma unroll
            for (int i = 0; i < 8; ++i) acc[r][i] += __shfl_xor(acc[r][i], off);
        }
    }
    // each lane adopts row (p>>2)&3, then stage 2 (xor 1, 2) finishes it
    const int rs = (p >> 2) & 3;
    float ssum = rs == 0 ? sum[0] : rs == 1 ? sum[1] : rs == 2 ? sum[2] : sum[3];
    float sacc[8];
#pragma unroll
    for (int i = 0; i < 8; ++i)
        sacc[i] = rs == 0 ? acc[0][i] : rs == 1 ? acc[1][i] : rs == 2 ? acc[2][i] : acc[3][i];
#pragma unroll
    for (int off = 1; off <= 2; off <<= 1) {
        ssum += __shfl_xor(ssum, off);
#pragma unroll
        for (int i = 0; i < 8; ++i) sacc[i] += __shfl_xor(sacc[i], off);
    }

    const int row = row0 + rs;
    const long grow = (long)b * SEQ + row;
    float inv = 1.0f / ssum;
    float out[8];
#pragma unroll
    for (int i = 0; i < 8; ++i) out[i] = sacc[i] * inv;

    // ---- proj + residual + LN1 ----
    const float4* xp = (const float4*)(x + grow * 8);
    float4 x0 = xp[0], x1 = xp[1];
    float xv[8] = {x0.x, x0.y, x0.z, x0.w, x1.x, x1.y, x1.z, x1.w};
    float y[8]; float m = 0.f;
#pragma unroll
    for (int j = 0; j < 8; ++j) {
        float v = Wb[j];
#pragma unroll
        for (int i = 0; i < 8; ++i) v += out[i] * W[i * 8 + j];
        y[j] = xv[j] + v;
        m += y[j];
    }
    m *= 0.125f;
    float var = 0.f;
#pragma unroll
    for (int j = 0; j < 8; ++j) { float d = y[j] - m; var += d * d; }
    var *= 0.125f;
    float rsg = rsqrtf(var + LNEPS);
    float xn[8];
#pragma unroll
    for (int j = 0; j < 8; ++j) xn[j] = g1[j] * (y[j] - m) * rsg + b1v[j];

    // ---- FFN: 8x8 -> qhead -> 8x8, residual + LN2 ----
    float h[8];
#pragma unroll
    for (int j = 0; j < 8; ++j) {
        float v = c1[j];
#pragma unroll
        for (int i = 0; i < 8; ++i) v += xn[i] * W1[i * 8 + j];
        h[j] = v;
    }
    float qf[8]; qhead(h, qf);
    float m2 = 0.f;
#pragma unroll
    for (int j = 0; j < 8; ++j) {
        float v = c2[j];
#pragma unroll
        for (int i = 0; i < 8; ++i) v += qf[i] * W2[i * 8 + j];
        y[j] = xn[j] + v;
        m2 += y[j];
    }
    m2 *= 0.125f;
    float var2 = 0.f;
#pragma unroll
    for (int j = 0; j < 8; ++j) { float d = y[j] - m2; var2 += d * d; }
    var2 *= 0.125f;
    float rs2 = rsqrtf(var2 + LNEPS);
    float xo[8];
#pragma unroll
    for (int j = 0; j < 8; ++j) xo[j] = g2[j] * (y[j] - m2) * rs2 + b2v[j];
    float z[8]; qhead(xo, z);

    if ((p & 3) == 0) {   // one writer per row
        float4* xw = (float4*)(x + grow * 8);
        float4* qw = (float4*)(qkv + grow * 8);
        xw[0] = make_float4(xo[0], xo[1], xo[2], xo[3]);
        xw[1] = make_float4(xo[4], xo[5], xo[6], xo[7]);
        qw[0] = make_float4(z[0], z[1], z[2], z[3]);
        qw[1] = make_float4(z[4], z[5], z[6], z[7]);
    }
}

// mean-pool over S + 8x10 classifier
__global__ __launch_bounds__(256) void pool_kernel(
    const float* __restrict__ x, const float* __restrict__ cls_w,
    const float* __restrict__ cls_b, float* __restrict__ out)
{
    __shared__ float ws[4][8];
    const int b = blockIdx.x;
    const int tid = threadIdx.x;
    float acc[8] = {0, 0, 0, 0, 0, 0, 0, 0};
    for (int s = tid; s < SEQ; s += 256) {
        const float4* p = (const float4*)(x + ((long)b * SEQ + s) * 8);
        float4 a0 = p[0], a1 = p[1];
        acc[0] += a0.x; acc[1] += a0.y; acc[2] += a0.z; acc[3] += a0.w;
        acc[4] += a1.x; acc[5] += a1.y; acc[6] += a1.z; acc[7] += a1.w;
    }
#pragma unroll
    for (int j = 0; j < 8; ++j) {
#pragma unroll
        for (int off = 1; off <= 32; off <<= 1) acc[j] += __shfl_xor(acc[j], off);
    }
    int wave = tid >> 6, lane = tid & 63;
    if (lane == 0) {
#pragma unroll
        for (int j = 0; j < 8; ++j) ws[wave][j] = acc[j];
    }
    __syncthreads();
    if (tid < 10) {
        float o = cls_b[tid];
#pragma unroll
        for (int j = 0; j < 8; ++j) {
            float pj = (ws[0][j] + ws[1][j] + ws[2][j] + ws[3][j]) * (1.0f / 1024.0f);
            o += pj * cls_w[j * 10 + tid];
        }
        out[b * 10 + tid] = o;
    }
}

extern "C" void kernel_launch(void* const* d_in, const int* in_sizes, int n_in,
                              void* d_out, int out_size, void* d_ws, size_t ws_size,
                              hipStream_t stream) {
    const int*   tokens = (const int*)d_in[0];
    const float* emb    = (const float*)d_in[1];
    const float* ln1_g  = (const float*)d_in[2];
    const float* ln1_b  = (const float*)d_in[3];
    const float* ln2_g  = (const float*)d_in[4];
    const float* ln2_b  = (const float*)d_in[5];
    const float* attn_w = (const float*)d_in[6];
    const float* attn_b = (const float*)d_in[7];
    const float* ffn_w1 = (const float*)d_in[8];
    const float* ffn_b1 = (const float*)d_in[9];
    const float* ffn_w2 = (const float*)d_in[10];
    const float* ffn_b2 = (const float*)d_in[11];
    const float* cls_w  = (const float*)d_in[12];
    const float* cls_b  = (const float*)d_in[13];

    float* x   = (float*)d_ws;                 // NROWS*8 f32 = 1 MB
    float* qkv = x + (long)NROWS * 8;          // NROWS*8 f32 = 1 MB

    embed_kernel<<<NROWS / 256, 256, 0, stream>>>(tokens, emb, x, qkv);
    for (int l = 0; l < 6; ++l) {
        layer_kernel<<<dim3(16, NBATCH), 256, 0, stream>>>(
            x, qkv,
            attn_w + l * 64, attn_b + l * 8,
            ln1_g + l * 8, ln1_b + l * 8,
            ffn_w1 + l * 64, ffn_b1 + l * 8,
            ffn_w2 + l * 64, ffn_b2 + l * 8,
            ln2_g + l * 8, ln2_b + l * 8);
    }
    pool_kernel<<<NBATCH, 256, 0, stream>>>(x, cls_w, cls_b, (float*)d_out);
}

// Round 6
// 111.044 us; speedup vs baseline: 4.7044x; 1.8349x over previous
//
#include <hip/hip_runtime.h>
#include <math.h>

#define EMB 8
#define SEQ 1024
#define NBATCH 32
#define NROWS (NBATCH * SEQ)
#define LNEPS 1e-5f

typedef __attribute__((ext_vector_type(8))) short bf16x8;
typedef __attribute__((ext_vector_type(16))) float f32x16;

union FragU { unsigned u[4]; bf16x8 s; };

__device__ __forceinline__ unsigned cvt_pk_bf16(float lo, float hi) {
    unsigned r;
    asm("v_cvt_pk_bf16_f32 %0, %1, %2" : "=v"(r) : "v"(lo), "v"(hi));
    return r;
}
__device__ __forceinline__ float bfu_lo(unsigned p) { return __uint_as_float(p << 16); }
__device__ __forceinline__ float bfu_hi(unsigned p) { return __uint_as_float(p & 0xFFFF0000u); }

// Closed-form quantum head: RX layer + Clifford (CNOT chain + H) conjugates
// each Z_i into a product of cos(x_j) (even/odd prefix products).
__device__ __forceinline__ void qhead(const float xv[8], float z[8]) {
    float c[8];
#pragma unroll
    for (int j = 0; j < 8; ++j) c[j] = __cosf(xv[j]);
    float e0 = c[0];
    float o1 = c[1];
    float e2 = e0 * c[2];
    float o3 = o1 * c[3];
    float e4 = e2 * c[4];
    float o5 = o3 * c[5];
    float e6 = e4 * c[6];
    z[0] = e0; z[1] = o1; z[2] = e2; z[3] = o3;
    z[4] = e4; z[5] = o5; z[6] = e6;
    z[7] = e6 * o5 * c[7];
}

// x = emb[tokens] + posenc ; qkv = qhead(x)
__global__ __launch_bounds__(256) void embed_kernel(
    const int* __restrict__ tokens, const float* __restrict__ emb,
    float* __restrict__ x, float* __restrict__ qkv)
{
    int r = blockIdx.x * 256 + threadIdx.x;
    int s = r & (SEQ - 1);
    int tok = tokens[r];
    const float* e = emb + (long)tok * EMB;
    float p = (float)s;
    float xv[8];
    xv[0] = e[0] + sinf(p);
    xv[1] = e[1] + cosf(p);
    xv[2] = e[2] + sinf(p * 0.1f);
    xv[3] = e[3] + cosf(p * 0.1f);
    xv[4] = e[4] + sinf(p * 0.01f);
    xv[5] = e[5] + cosf(p * 0.01f);
    xv[6] = e[6] + sinf(p * 0.001f);
    xv[7] = e[7] + cosf(p * 0.001f);
    float z[8]; qhead(xv, z);
    float4* xo = (float4*)(x + (long)r * 8);
    float4* qo = (float4*)(qkv + (long)r * 8);
    xo[0] = make_float4(xv[0], xv[1], xv[2], xv[3]);
    xo[1] = make_float4(xv[4], xv[5], xv[6], xv[7]);
    qo[0] = make_float4(z[0], z[1], z[2], z[3]);
    qo[1] = make_float4(z[4], z[5], z[6], z[7]);
}

// One transformer block via MFMA attention, swapped-QK^T + hi/lo precision.
// Grid (16, NBATCH), 4 waves: wave w -> q-tile (w>>1), key-half (w&1).
// Scores: mfma(A=K_tile, B=Q_tile) -> lane ln holds s(q-row ln, keys rr(g,h));
// rr-map == A k-slot map, so exp'd scores feed PV's A operand in-lane.
// hi/lo: s = kh*qh + kl*qh + kh*ql (2 MFMAs, spare K-slots carry lo channel).
// PV: P*V_hi + P*V_lo; ones-column in V_hi col 8 -> exact denominator.
__global__ __launch_bounds__(256, 2) void layer_kernel(
    float* __restrict__ x, float* __restrict__ qkv,
    const float* __restrict__ W, const float* __restrict__ Wb,
    const float* __restrict__ g1, const float* __restrict__ b1v,
    const float* __restrict__ W1, const float* __restrict__ c1,
    const float* __restrict__ W2, const float* __restrict__ c2,
    const float* __restrict__ g2, const float* __restrict__ b2v)
{
    __shared__ unsigned short KbH[SEQ * 8];      // 16 KB bf16(beta*z)
    __shared__ unsigned short KbL[SEQ * 8];      // 16 KB bf16 residual
    __shared__ unsigned short VtH[8][1032];      // bf16(z) transposed
    __shared__ unsigned short VtL[8][1032];      // residual, transposed
    __shared__ float Olds[4][32][9];             // per-wave PV partials

    const int b = blockIdx.y;
    const int wgx = blockIdx.x;
    const int tid = threadIdx.x;
    const float beta = 0.71423162f;   // sqrt(log2(e)/sqrt(8))

    // ---------------- stage qkv -> KbH/KbL, VtH/VtL ----------------
    {
        const float* src = qkv + (long)b * SEQ * EMB;
        const int k0 = tid * 4;
        float v[4][8];
#pragma unroll
        for (int i = 0; i < 4; ++i) {
            float4 a0 = *(const float4*)(src + (long)(k0 + i) * 8);
            float4 a1 = *(const float4*)(src + (long)(k0 + i) * 8 + 4);
            v[i][0] = a0.x; v[i][1] = a0.y; v[i][2] = a0.z; v[i][3] = a0.w;
            v[i][4] = a1.x; v[i][5] = a1.y; v[i][6] = a1.z; v[i][7] = a1.w;
        }
        // K rows: hi = bf16(beta*v), lo = exact residual of stored bits
#pragma unroll
        for (int i = 0; i < 4; ++i) {
            float bv[8];
#pragma unroll
            for (int c = 0; c < 8; ++c) bv[c] = v[i][c] * beta;
            unsigned ph[4], pl[4];
#pragma unroll
            for (int d = 0; d < 4; ++d) {
                ph[d] = cvt_pk_bf16(bv[2 * d], bv[2 * d + 1]);
                float l0 = bv[2 * d] - bfu_lo(ph[d]);
                float l1 = bv[2 * d + 1] - bfu_hi(ph[d]);
                pl[d] = cvt_pk_bf16(l0, l1);
            }
            unsigned* dh = (unsigned*)&KbH[(k0 + i) * 8];
            unsigned* dl = (unsigned*)&KbL[(k0 + i) * 8];
#pragma unroll
            for (int d = 0; d < 4; ++d) { dh[d] = ph[d]; dl[d] = pl[d]; }
        }
        // V columns (transposed): hi = bf16(v), lo = residual
#pragma unroll
        for (int c = 0; c < 8; ++c) {
            unsigned h0 = cvt_pk_bf16(v[0][c], v[1][c]);
            unsigned h1 = cvt_pk_bf16(v[2][c], v[3][c]);
            unsigned l0 = cvt_pk_bf16(v[0][c] - bfu_lo(h0), v[1][c] - bfu_hi(h0));
            unsigned l1 = cvt_pk_bf16(v[2][c] - bfu_lo(h1), v[3][c] - bfu_hi(h1));
            unsigned* dh = (unsigned*)&VtH[c][k0];
            unsigned* dl = (unsigned*)&VtL[c][k0];
            dh[0] = h0; dh[1] = h1; dl[0] = l0; dl[1] = l1;
        }
    }
    __syncthreads();

    const int w = tid >> 6;
    const int lane = tid & 63;
    const int ln = lane & 31;
    const int h = lane >> 5;
    const int qbase = wgx * 64 + (w >> 1) * 32;
    const int khalf = w & 1;

    // Q B-frags (col = ln = this lane's q-row): qfB = (q_hi || q_hi),
    // qfB2 = (q_lo || 0).
    FragU qfB, qfB2;
    {
        const unsigned* qh = (const unsigned*)&KbH[(qbase + ln) * 8 + 4 * h];
        const unsigned* ql = (const unsigned*)&KbL[(qbase + ln) * 8 + 4 * h];
        qfB.u[0] = qh[0]; qfB.u[1] = qh[1]; qfB.u[2] = qh[0]; qfB.u[3] = qh[1];
        qfB2.u[0] = ql[0]; qfB2.u[1] = ql[1]; qfB2.u[2] = 0; qfB2.u[3] = 0;
    }

    f32x16 zc;
#pragma unroll
    for (int i = 0; i < 16; ++i) zc[i] = 0.f;
    f32x16 acc = zc;

    for (int t = 0; t < 16; ++t) {
        const int kbase = (khalf * 16 + t) * 32;
        // K A-frags (row = ln = key within tile): kfA = (k_hi || k_lo),
        // kfA2 = (k_hi || 0).
        FragU kfA, kfA2;
        {
            const unsigned* kh = (const unsigned*)&KbH[(kbase + ln) * 8 + 4 * h];
            const unsigned* kl = (const unsigned*)&KbL[(kbase + ln) * 8 + 4 * h];
            kfA.u[0] = kh[0]; kfA.u[1] = kh[1]; kfA.u[2] = kl[0]; kfA.u[3] = kl[1];
            kfA2.u[0] = kh[0]; kfA2.u[1] = kh[1]; kfA2.u[2] = 0; kfA2.u[3] = 0;
        }
        // s[g] = score(q-row qbase+ln, key kbase+rr(g,h))
        f32x16 s = __builtin_amdgcn_mfma_f32_32x32x16_bf16(kfA2.s, qfB2.s, zc, 0, 0, 0);
        s = __builtin_amdgcn_mfma_f32_32x32x16_bf16(kfA.s, qfB.s, s, 0, 0, 0);
        float p[16];
#pragma unroll
        for (int g = 0; g < 16; ++g) p[g] = exp2f(s[g]);

        // rr-map == A k-slot map -> p feeds PV A-operand directly
        FragU a1, a2;
#pragma unroll
        for (int vi = 0; vi < 4; ++vi) {
            a1.u[vi] = cvt_pk_bf16(p[2 * vi], p[2 * vi + 1]);
            a2.u[vi] = cvt_pk_bf16(p[8 + 2 * vi], p[8 + 2 * vi + 1]);
        }
        // V B-frags: col=ln (0..7 real, 8: hi=ones -> denominator, lo=0)
        FragU v1h, v2h, v1l, v2l;
        if (ln < 8) {
            const unsigned* r0 = (const unsigned*)&VtH[ln][kbase + 4 * h];
            const unsigned* r1 = (const unsigned*)&VtH[ln][kbase + 8 + 4 * h];
            const unsigned* r2 = (const unsigned*)&VtH[ln][kbase + 16 + 4 * h];
            const unsigned* r3 = (const unsigned*)&VtH[ln][kbase + 24 + 4 * h];
            v1h.u[0] = r0[0]; v1h.u[1] = r0[1]; v1h.u[2] = r1[0]; v1h.u[3] = r1[1];
            v2h.u[0] = r2[0]; v2h.u[1] = r2[1]; v2h.u[2] = r3[0]; v2h.u[3] = r3[1];
            const unsigned* s0 = (const unsigned*)&VtL[ln][kbase + 4 * h];
            const unsigned* s1 = (const unsigned*)&VtL[ln][kbase + 8 + 4 * h];
            const unsigned* s2 = (const unsigned*)&VtL[ln][kbase + 16 + 4 * h];
            const unsigned* s3 = (const unsigned*)&VtL[ln][kbase + 24 + 4 * h];
            v1l.u[0] = s0[0]; v1l.u[1] = s0[1]; v1l.u[2] = s1[0]; v1l.u[3] = s1[1];
            v2l.u[0] = s2[0]; v2l.u[1] = s2[1]; v2l.u[2] = s3[0]; v2l.u[3] = s3[1];
        } else if (ln == 8) {
#pragma unroll
            for (int i = 0; i < 4; ++i) {
                v1h.u[i] = 0x3F803F80u; v2h.u[i] = 0x3F803F80u;
                v1l.u[i] = 0; v2l.u[i] = 0;
            }
        } else {
#pragma unroll
            for (int i = 0; i < 4; ++i) { v1h.u[i] = 0; v2h.u[i] = 0; v1l.u[i] = 0; v2l.u[i] = 0; }
        }
        acc = __builtin_amdgcn_mfma_f32_32x32x16_bf16(a1.s, v1h.s, acc, 0, 0, 0);
        acc = __builtin_amdgcn_mfma_f32_32x32x16_bf16(a2.s, v2h.s, acc, 0, 0, 0);
        acc = __builtin_amdgcn_mfma_f32_32x32x16_bf16(a1.s, v1l.s, acc, 0, 0, 0);
        acc = __builtin_amdgcn_mfma_f32_32x32x16_bf16(a2.s, v2l.s, acc, 0, 0, 0);
    }

    // ---- dump per-wave PV partials: acc[g] = out[q-row rr(g,h)][col ln] ----
    if (ln <= 8) {
#pragma unroll
        for (int g = 0; g < 16; ++g) {
            Olds[w][(g & 3) + 8 * (g >> 2) + 4 * h][ln] = acc[g];
        }
    }
    __syncthreads();

    // ---- epilogue: 64 rows, one thread each ----
    if (tid < 64) {
        const int r = tid;
        const int rr = r & 31;
        const int w0 = (r >> 5) * 2;
        float o[9];
#pragma unroll
        for (int c = 0; c < 9; ++c) o[c] = Olds[w0][rr][c] + Olds[w0 + 1][rr][c];
        float inv = 1.0f / o[8];
        float out[8];
#pragma unroll
        for (int c = 0; c < 8; ++c) out[c] = o[c] * inv;

        const long grow = (long)b * SEQ + wgx * 64 + r;
        const float4* xp = (const float4*)(x + grow * 8);
        float4 x0 = xp[0], x1 = xp[1];
        float xv[8] = {x0.x, x0.y, x0.z, x0.w, x1.x, x1.y, x1.z, x1.w};

        float y[8]; float m = 0.f;
#pragma unroll
        for (int j = 0; j < 8; ++j) {
            float vv = Wb[j];
#pragma unroll
            for (int i = 0; i < 8; ++i) vv += out[i] * W[i * 8 + j];
            y[j] = xv[j] + vv;
            m += y[j];
        }
        m *= 0.125f;
        float var = 0.f;
#pragma unroll
        for (int j = 0; j < 8; ++j) { float d = y[j] - m; var += d * d; }
        var *= 0.125f;
        float rsg = rsqrtf(var + LNEPS);
        float xn[8];
#pragma unroll
        for (int j = 0; j < 8; ++j) xn[j] = g1[j] * (y[j] - m) * rsg + b1v[j];

        float hh[8];
#pragma unroll
        for (int j = 0; j < 8; ++j) {
            float vv = c1[j];
#pragma unroll
            for (int i = 0; i < 8; ++i) vv += xn[i] * W1[i * 8 + j];
            hh[j] = vv;
        }
        float qff[8]; qhead(hh, qff);
        float m2 = 0.f;
#pragma unroll
        for (int j = 0; j < 8; ++j) {
            float vv = c2[j];
#pragma unroll
            for (int i = 0; i < 8; ++i) vv += qff[i] * W2[i * 8 + j];
            y[j] = xn[j] + vv;
            m2 += y[j];
        }
        m2 *= 0.125f;
        float var2 = 0.f;
#pragma unroll
        for (int j = 0; j < 8; ++j) { float d = y[j] - m2; var2 += d * d; }
        var2 *= 0.125f;
        float rs2 = rsqrtf(var2 + LNEPS);
        float xo[8];
#pragma unroll
        for (int j = 0; j < 8; ++j) xo[j] = g2[j] * (y[j] - m2) * rs2 + b2v[j];
        float z[8]; qhead(xo, z);

        float4* xw = (float4*)(x + grow * 8);
        float4* qw = (float4*)(qkv + grow * 8);
        xw[0] = make_float4(xo[0], xo[1], xo[2], xo[3]);
        xw[1] = make_float4(xo[4], xo[5], xo[6], xo[7]);
        qw[0] = make_float4(z[0], z[1], z[2], z[3]);
        qw[1] = make_float4(z[4], z[5], z[6], z[7]);
    }
}

// mean-pool over S + 8x10 classifier
__global__ __launch_bounds__(256) void pool_kernel(
    const float* __restrict__ x, const float* __restrict__ cls_w,
    const float* __restrict__ cls_b, float* __restrict__ out)
{
    __shared__ float ws[4][8];
    const int b = blockIdx.x;
    const int tid = threadIdx.x;
    float acc[8] = {0, 0, 0, 0, 0, 0, 0, 0};
    for (int s = tid; s < SEQ; s += 256) {
        const float4* p = (const float4*)(x + ((long)b * SEQ + s) * 8);
        float4 a0 = p[0], a1 = p[1];
        acc[0] += a0.x; acc[1] += a0.y; acc[2] += a0.z; acc[3] += a0.w;
        acc[4] += a1.x; acc[5] += a1.y; acc[6] += a1.z; acc[7] += a1.w;
    }
#pragma unroll
    for (int j = 0; j < 8; ++j) {
#pragma unroll
        for (int off = 1; off <= 32; off <<= 1) acc[j] += __shfl_xor(acc[j], off);
    }
    int wave = tid >> 6, lane = tid & 63;
    if (lane == 0) {
#pragma unroll
        for (int j = 0; j < 8; ++j) ws[wave][j] = acc[j];
    }
    __syncthreads();
    if (tid < 10) {
        float o = cls_b[tid];
#pragma unroll
        for (int j = 0; j < 8; ++j) {
            float pj = (ws[0][j] + ws[1][j] + ws[2][j] + ws[3][j]) * (1.0f / 1024.0f);
            o += pj * cls_w[j * 10 + tid];
        }
        out[b * 10 + tid] = o;
    }
}

extern "C" void kernel_launch(void* const* d_in, const int* in_sizes, int n_in,
                              void* d_out, int out_size, void* d_ws, size_t ws_size,
                              hipStream_t stream) {
    const int*   tokens = (const int*)d_in[0];
    const float* emb    = (const float*)d_in[1];
    const float* ln1_g  = (const float*)d_in[2];
    const float* ln1_b  = (const float*)d_in[3];
    const float* ln2_g  = (const float*)d_in[4];
    const float* ln2_b  = (const float*)d_in[5];
    const float* attn_w = (const float*)d_in[6];
    const float* attn_b = (const float*)d_in[7];
    const float* ffn_w1 = (const float*)d_in[8];
    const float* ffn_b1 = (const float*)d_in[9];
    const float* ffn_w2 = (const float*)d_in[10];
    const float* ffn_b2 = (const float*)d_in[11];
    const float* cls_w  = (const float*)d_in[12];
    const float* cls_b  = (const float*)d_in[13];

    float* x   = (float*)d_ws;                 // NROWS*8 f32 = 1 MB
    float* qkv = x + (long)NROWS * 8;          // NROWS*8 f32 = 1 MB

    embed_kernel<<<NROWS / 256, 256, 0, stream>>>(tokens, emb, x, qkv);
    for (int l = 0; l < 6; ++l) {
        layer_kernel<<<dim3(16, NBATCH), 256, 0, stream>>>(
            x, qkv,
            attn_w + l * 64, attn_b + l * 8,
            ln1_g + l * 8, ln1_b + l * 8,
            ffn_w1 + l * 64, ffn_b1 + l * 8,
            ffn_w2 + l * 64, ffn_b2 + l * 8,
            ln2_g + l * 8, ln2_b + l * 8);
    }
    pool_kernel<<<NBATCH, 256, 0, stream>>>(x, cls_w, cls_b, (float*)d_out);
}